// Round 5
// baseline (509.183 us; speedup 1.0000x reference)
//
#include <hip/hip_runtime.h>
#include <hip/hip_bf16.h>
#include <stdint.h>

// GNN_758: stacked RelGraphConv x2.  N=50000, E=1.6M, D=128, R=20.
// agg[dst] = sum_r (sum_{e in rel r -> dst} h[src]) @ W[r]; self-loop = rel 20.
// R12: MFMA-indicator aggregation. The per-(dst,rel) edge sum IS a matmul:
//   S_r = Ind(16x32 0/1) @ H_batch(32x128), done with mfma_16x16x32_bf16.
// - edges sorted per tile by REL only (20 bins; dst disambiguated by Ind)
// - staged H in Hs[fc][32 edge][16 flow] (conflict-free [32][16] subtiling);
//   B-frags via ds_read_b64_tr_b16 (per-lane addr = base + lane*8B)
// - k-slot<->edge map perm(q,j) = j<4 ? q*4+j : 16+q*4+(j-4); indicator and
//   WP k-pack use the same perm -> consistent everywhere
// - gemm2 (S_r @ W[r]) A-frag via tr-read from SbT[feat128][dst16]
// - 512 thr / 8 waves; wave w owns feat-tile w (gemm1) and out-tile w (gemm2)
//   -> acc = 1 f32x4 each, no cross-wave reduce. LDS 23.3KB -> 4 blk/CU = 100%.
// - batch loads issued one batch ahead (flat (rel,batch) iterator) to hide HBM.

#define NN 50000
#define NE 1600000
#define DIM 128
#define NREL 20
#define NRELP 21
#define TILE 16
#define NTILE (NN / TILE)          // 3125
#define CHB 200                    // chunk blocks for count/scatter
#define CHE (NE / CHB)             // 8000 edges per chunk block
#define TT_N (NTILE * CHB)         // 625000 (tile,blk) table
#define SCAN_EPB 2048
#define NBLK_TT ((TT_N + SCAN_EPB - 1) / SCAN_EPB)   // 306
#define ESP_CAP 640                // staged payloads per block (mean 512, +5.7sd)
#define PACKED_ELEMS (2 * NRELP * 4 * 8 * 64 * 8)    // 688128

typedef __attribute__((ext_vector_type(8))) short short8;
typedef __attribute__((ext_vector_type(4))) float f32x4;

__device__ __forceinline__ unsigned short f32_to_bf16_raw(float f) {
  union { float f; unsigned u; } c; c.f = f;
  unsigned u = c.u;
  return (unsigned short)((u + 0x7fffu + ((u >> 16) & 1u)) >> 16);  // RNE
}
__device__ __forceinline__ unsigned cvt_pk_bf16(float lo, float hi) {
  unsigned r;   // bits 0-15 = bf16(lo), 16-31 = bf16(hi), RNE (gfx950)
  asm("v_cvt_pk_bf16_f32 %0, %1, %2" : "=v"(r) : "v"(lo), "v"(hi));
  return r;
}

// ---------------- fp32 -> bf16 (x4), nontemporal stores ----------------
__global__ void cvt_bf16_kernel(const float* __restrict__ in,
                                unsigned short* __restrict__ out, int n4) {
  int i = blockIdx.x * 256 + threadIdx.x;
  if (i < n4) {
    float4 f = ((const float4*)in)[i];
    unsigned long long p =
        (unsigned long long)cvt_pk_bf16(f.x, f.y)
      | ((unsigned long long)cvt_pk_bf16(f.z, f.w) << 32);
    __builtin_nontemporal_store(p, (unsigned long long*)out + i);  // clean -> L3
  }
}

// ---------------- pack W (+loop_w as rel 20) into B-fragment order ----------------
// WP flat: ((((l*21 + r)*4 + ks)*8 + nc)*64 + lane)*8
// k-slot j of lane maps to k = ks*32 + perm(lane>>4, j), matching the tr-read
// element order used for the gemm2 A-fragment.
__global__ void pack_w_kernel(const float* __restrict__ W,
                              const float* __restrict__ loop_w,
                              unsigned short* __restrict__ WP) {
  int idx = blockIdx.x * 256 + threadIdx.x;
  if (idx >= PACKED_ELEMS) return;
  int j = idx & 7;       int t = idx >> 3;
  int lane = t & 63;     t >>= 6;
  int nc = t & 7;        t >>= 3;
  int ks = t & 3;        t >>= 2;
  int r = t % NRELP;     int l = t / NRELP;
  int kq = lane >> 4;
  int k = ks * 32 + ((j < 4) ? (kq * 4 + j) : (16 + kq * 4 + (j - 4)));
  int n = nc * 16 + (lane & 15);
  float v = (r < NREL) ? W[(((size_t)l * NREL + r) * DIM + k) * DIM + n]
                       : loop_w[((size_t)l * DIM + k) * DIM + n];
  WP[idx] = f32_to_bf16_raw(v);
}

// ---------------- two-level counting sort (no device atomics) ----------------
__global__ __launch_bounds__(256) void tile_count_kernel(
    const int* __restrict__ dst, unsigned int* __restrict__ tt) {
  __shared__ unsigned int hist[NTILE];           // 12.5 KB
  for (int i = threadIdx.x; i < NTILE; i += 256) hist[i] = 0u;
  __syncthreads();
  const int base = blockIdx.x * CHE;
  for (int i = base + threadIdx.x; i < base + CHE; i += 256)
    atomicAdd(&hist[dst[i] >> 4], 1u);           // LDS atomic
  __syncthreads();
  for (int i = threadIdx.x; i < NTILE; i += 256)
    tt[(size_t)i * CHB + blockIdx.x] = hist[i];  // (bin, blk) layout for scan
}

__global__ void scanA_kernel(const unsigned int* __restrict__ in,
                             unsigned int* __restrict__ out,
                             unsigned int* __restrict__ btot, int n) {
  __shared__ unsigned int buf[256];
  int tid = threadIdx.x;
  int base = blockIdx.x * SCAN_EPB + tid * 8;
  unsigned int v[8], p[8], s = 0;
#pragma unroll
  for (int j = 0; j < 8; ++j) {
    v[j] = (base + j < n) ? in[base + j] : 0u;
    p[j] = s; s += v[j];
  }
  buf[tid] = s;
  __syncthreads();
  for (int d = 1; d < 256; d <<= 1) {
    unsigned int a = (tid >= d) ? buf[tid - d] : 0u;
    __syncthreads();
    buf[tid] += a;
    __syncthreads();
  }
  unsigned int excl = buf[tid] - s;
#pragma unroll
  for (int j = 0; j < 8; ++j)
    if (base + j < n) out[base + j] = excl + p[j];
  if (tid == 255) btot[blockIdx.x] = buf[255];
}

__global__ void scanB_kernel(unsigned int* __restrict__ btot, int nblk) {
  __shared__ unsigned int buf[1024];
  int t = threadIdx.x;
  unsigned int v = (t < nblk) ? btot[t] : 0u;
  buf[t] = v;
  __syncthreads();
  for (int d = 1; d < 1024; d <<= 1) {
    unsigned int a = (t >= d) ? buf[t - d] : 0u;
    __syncthreads();
    buf[t] += a;
    __syncthreads();
  }
  if (t < nblk) btot[t] = buf[t] - v;   // exclusive
}

__global__ void scanC_kernel(const unsigned int* __restrict__ btot,
                             unsigned int* __restrict__ out, int n) {
  int base = blockIdx.x * SCAN_EPB + threadIdx.x * 8;
  unsigned int add = btot[blockIdx.x];
#pragma unroll
  for (int j = 0; j < 8; ++j)
    if (base + j < n) out[base + j] += add;
}

// Level-1 scatter: payload u32 = src | dstLow4<<16 | rel<<20, tile-bucketed.
__global__ __launch_bounds__(256) void tile_scatter_kernel(
    const int* __restrict__ src, const int* __restrict__ dst,
    const int* __restrict__ et, const unsigned int* __restrict__ tts,
    unsigned int* __restrict__ ep) {
  __shared__ unsigned int cur[NTILE];            // 12.5 KB
  for (int i = threadIdx.x; i < NTILE; i += 256)
    cur[i] = tts[(size_t)i * CHB + blockIdx.x];
  __syncthreads();
  const int base = blockIdx.x * CHE;
  for (int i = base + threadIdx.x; i < base + CHE; i += 256) {
    int d = dst[i];
    unsigned int pos = atomicAdd(&cur[d >> 4], 1u);   // LDS atomic
    ep[pos] = (unsigned int)src[i] | ((unsigned int)(d & 15) << 16)
            | ((unsigned int)et[i] << 20);
  }
}

// Level 2: per-tile 20-bin rel sort -> relofs[tile*21 + r] + esp (u32 payload).
__global__ __launch_bounds__(512) void tile_sort_kernel(
    const unsigned int* __restrict__ ep, const unsigned int* __restrict__ tts,
    unsigned int* __restrict__ esp, unsigned int* __restrict__ relofs) {
  __shared__ unsigned int hist[NREL];
  __shared__ unsigned int cur[NREL];
  const int t = threadIdx.x;
  const int tile = blockIdx.x;
  const unsigned int start = tts[(size_t)tile * CHB];
  const unsigned int end = (tile + 1 < NTILE) ? tts[(size_t)(tile + 1) * CHB]
                                              : (unsigned int)NE;
  const int cnt = (int)(end - start);
  if (t < NREL) hist[t] = 0u;
  __syncthreads();
  for (int i = t; i < cnt; i += 512)
    atomicAdd(&hist[ep[start + i] >> 20], 1u);
  __syncthreads();
  if (t == 0) {
    unsigned int run = start;
    for (int r = 0; r < NREL; ++r) {
      relofs[(size_t)tile * NRELP + r] = run;
      cur[r] = run;
      run += hist[r];
    }
    relofs[(size_t)tile * NRELP + NREL] = end;
  }
  __syncthreads();
  for (int i = t; i < cnt; i += 512) {
    unsigned int p = ep[start + i];
    unsigned int pos = atomicAdd(&cur[p >> 20], 1u);
    esp[pos] = p & 0xFFFFFu;       // src | dstLocal<<16
  }
}

// ---------------- fused RGCN layer (MFMA-indicator) ----------------
// 3125 blocks x 512 threads (8 waves). LDS 23.3KB; 4 blocks/CU (wave cap).
__global__ __launch_bounds__(512, 8) void rgcn_layer_kernel(
    const unsigned short* __restrict__ hb,    // [N,128] bf16
    const unsigned short* __restrict__ WP,    // packed weights
    const float* __restrict__ bias,           // [128] this layer
    int layer,
    const unsigned int* __restrict__ relofs,  // [NTILE*21] rel offsets (+end)
    const unsigned int* __restrict__ esp,     // [E] payload src|dstLocal<<16
    float* __restrict__ outf,                 // fp32 out (layer 1) or null
    unsigned short* __restrict__ outb)        // bf16 out (layer 0) or null
{
  __shared__ __align__(16) unsigned short Hs[2][4096];  // 16 KB: [fc8][e32][flow16]
  __shared__ __align__(16) unsigned short SbT[2048];    // 4 KB: [feat128][dst16]
  __shared__ unsigned int esp_l[ESP_CAP];               // 2.5 KB
  __shared__ unsigned short dl[2][32];                  // dstLocal per slot
  __shared__ unsigned int ro_l[NRELP];

  const int tid  = threadIdx.x;
  const int lane = tid & 63;
  const int w    = tid >> 6;        // wave 0..7 = fc (gemm1) = nc (gemm2)
  const int q    = lane >> 4;
  const int mm   = lane & 15;
  const int dst_base = blockIdx.x * TILE;

  if (tid < NRELP) ro_l[tid] = relofs[(size_t)blockIdx.x * NRELP + tid];
  __syncthreads();
  const int e0 = (int)ro_l[0];
  const int etot = (int)ro_l[NREL] - e0;
  const bool use_lds = (etot <= ESP_CAP);
  if (use_lds)
    for (int i = tid; i < etot; i += 512) esp_l[i] = esp[e0 + i];
  __syncthreads();

  const unsigned hs_base  = (unsigned)(size_t)&Hs[0][0];
  const unsigned sbt_base = (unsigned)(size_t)&SbT[0];

  // staging slot for this thread: edge e = tid>>4, feat-16B piece sm = tid&15
  const int se = tid >> 4;          // 0..31
  const int sm = tid & 15;

  auto cntr = [&](int r) -> int {
    return (r < NREL) ? (int)(ro_l[r + 1] - ro_l[r]) : 16;
  };
  // find first non-empty rel
  auto next_re = [&](int r, int b) {
    // returns encoded r*16+b of next batch, or -1
    int nb = (cntr(r) + 31) >> 5;
    if (r == NREL) nb = 1;
    if (b + 1 < nb) return r * 32 + (b + 1);
    int rn = r + 1;
    while (rn < NREL && cntr(rn) == 0) ++rn;
    if (rn > NREL) return -1;
    return rn * 32;          // (rn, 0); rn may be NREL (self-loop)
  };

  short8 pv; int pd;
  auto issue_load = [&](int r, int b) {
    int src, dL;
    if (r < NREL) {
      int ge = (int)ro_l[r] + b * 32 + se;
      bool pad = ge >= (int)ro_l[r + 1];
      int gi = pad ? ((int)ro_l[r + 1] - 1) : ge;
      unsigned p = use_lds ? esp_l[gi - e0] : esp[gi];
      src = (int)(p & 0xFFFFu);
      dL = pad ? 31 : (int)((p >> 16) & 15u);
    } else {
      bool pad = se >= 16;
      src = dst_base + (pad ? 15 : se);
      dL = pad ? 31 : se;
    }
    pd = dL;
    pv = *(const short8*)(hb + (size_t)src * DIM + sm * 8);
  };

  f32x4 accS = (f32x4){0.f, 0.f, 0.f, 0.f};
  f32x4 accO = (f32x4){0.f, 0.f, 0.f, 0.f};

  // first batch
  int rs = 0;
  while (rs < NREL && cntr(rs) == 0) ++rs;
  int bs = 0;
  issue_load(rs, bs);
  int buf = 0;

  while (true) {
    // ---- stage write (batch rs,bs) ----
    if (sm == 0) dl[buf][se] = (unsigned short)pd;
    *(short8*)&Hs[buf][(sm >> 1) * 512 + se * 16 + (sm & 1) * 8] = pv;

    const int nxt = next_re(rs, bs);
    if (nxt >= 0) issue_load(nxt >> 5, nxt & 31);   // prefetch next batch
    __syncthreads();

    // ---- gemm1: accS += Ind @ H_batch  (wave w owns feat-tile fc = w) ----
    short8 A;
#pragma unroll
    for (int j = 0; j < 8; ++j) {
      int e = (j < 4) ? (q * 4 + j) : (16 + q * 4 + (j - 4));
      A[j] = (dl[buf][e] == mm) ? (short)0x3F80 : (short)0;
    }
    {
      unsigned ad = hs_base + (unsigned)buf * 8192u + (unsigned)w * 1024u
                  + (unsigned)lane * 8u;
      unsigned long long t0, t1;
      asm volatile("ds_read_b64_tr_b16 %0, %1" : "=v"(t0) : "v"(ad) : "memory");
      asm volatile("ds_read_b64_tr_b16 %0, %1" : "=v"(t1) : "v"(ad + 512u) : "memory");
      asm volatile("s_waitcnt lgkmcnt(0)" ::: "memory");
      __builtin_amdgcn_sched_barrier(0);
      union { struct { unsigned long long a, b; } u; short8 s; } pk;
      pk.u.a = t0; pk.u.b = t1;
      accS = __builtin_amdgcn_mfma_f32_16x16x32_bf16(A, pk.s, accS, 0, 0, 0);
    }

    // ---- rel boundary: flush S_r and do gemm2 ----
    const bool rel_done = (nxt < 0) || ((nxt >> 5) != rs);
    if (rel_done) {
      // flush: lane holds S[dst=q*4+i][feat=w*16+mm] for i=0..3
      unsigned p0 = cvt_pk_bf16(accS[0], accS[1]);
      unsigned p1 = cvt_pk_bf16(accS[2], accS[3]);
      *(uint2*)&SbT[w * 256 + mm * 16 + q * 4] = make_uint2(p0, p1);
      accS = (f32x4){0.f, 0.f, 0.f, 0.f};
      __syncthreads();
      // gemm2: accO += S_r @ W[r]; wave w owns out-tile nc = w
      const unsigned short* bp =
          WP + ((((size_t)(layer * NRELP + rs) * 4) * 8 + w) * 64 + lane) * 8;
#pragma unroll
      for (int ks = 0; ks < 4; ++ks) {
        unsigned ad = sbt_base + (unsigned)ks * 1024u + (unsigned)lane * 8u;
        unsigned long long t0, t1;
        asm volatile("ds_read_b64_tr_b16 %0, %1" : "=v"(t0) : "v"(ad) : "memory");
        asm volatile("ds_read_b64_tr_b16 %0, %1" : "=v"(t1) : "v"(ad + 512u) : "memory");
        short8 B = *(const short8*)(bp + (size_t)ks * 4096);
        asm volatile("s_waitcnt lgkmcnt(0)" ::: "memory");
        __builtin_amdgcn_sched_barrier(0);
        union { struct { unsigned long long a, b; } u; short8 s; } pk;
        pk.u.a = t0; pk.u.b = t1;
        accO = __builtin_amdgcn_mfma_f32_16x16x32_bf16(pk.s, B, accO, 0, 0, 0);
      }
      // no barrier needed: next flush is preceded by >=1 batch barrier
    }
    if (nxt < 0) break;
    rs = nxt >> 5; bs = nxt & 31; buf ^= 1;
  }

  // ---- epilogue: wave w stores out-tile nc = w ----
  const int col = w * 16 + mm;
  const float bv = bias[col];
  if (outb) {
#pragma unroll
    for (int i = 0; i < 4; ++i)
      outb[(size_t)(dst_base + q * 4 + i) * DIM + col] =
          f32_to_bf16_raw(accO[i] + bv);
  } else {
#pragma unroll
    for (int i = 0; i < 4; ++i)
      outf[(size_t)(dst_base + q * 4 + i) * DIM + col] = accO[i] + bv;
  }
}

// ---------------- launch ----------------
extern "C" void kernel_launch(void* const* d_in, const int* in_sizes, int n_in,
                              void* d_out, int out_size, void* d_ws, size_t ws_size,
                              hipStream_t stream) {
  const float* h0     = (const float*)d_in[0];
  const float* W      = (const float*)d_in[1];
  const float* loop_w = (const float*)d_in[2];
  const float* bias   = (const float*)d_in[3];
  const int* esrc     = (const int*)d_in[4];
  const int* edst     = (const int*)d_in[5];
  const int* etyp     = (const int*)d_in[6];
  float* out = (float*)d_out;

  char* ws = (char*)d_ws;
  size_t off = 0;
  auto alloc = [&](size_t bytes) -> void* {
    void* p = ws + off;
    off = (off + bytes + 255) & ~(size_t)255;
    return p;
  };
  unsigned short* hb0   = (unsigned short*)alloc((size_t)NN * DIM * 2);   // 12.8 MB
  unsigned short* hb1   = (unsigned short*)alloc((size_t)NN * DIM * 2);   // 12.8 MB
  unsigned short* WP    = (unsigned short*)alloc((size_t)PACKED_ELEMS * 2);
  unsigned int*   tt    = (unsigned int*)alloc((size_t)(TT_N + 1) * 4);   // 2.5 MB
  unsigned int*   tts   = (unsigned int*)alloc((size_t)(TT_N + 1) * 4);   // 2.5 MB
  unsigned int*   btot  = (unsigned int*)alloc((size_t)NBLK_TT * 4);
  unsigned int*   ep    = (unsigned int*)alloc((size_t)NE * 4);           // 6.4 MB
  unsigned int*   esp   = (unsigned int*)alloc((size_t)NE * 4);           // 6.4 MB
  unsigned int*   relofs= (unsigned int*)alloc((size_t)(NTILE * NRELP + 1) * 4);

  tile_count_kernel<<<CHB, 256, 0, stream>>>(edst, tt);
  scanA_kernel<<<NBLK_TT, 256, 0, stream>>>(tt, tts, btot, TT_N);
  scanB_kernel<<<1, 1024, 0, stream>>>(btot, NBLK_TT);
  scanC_kernel<<<NBLK_TT, 256, 0, stream>>>(btot, tts, TT_N);
  tile_scatter_kernel<<<CHB, 256, 0, stream>>>(esrc, edst, etyp, tts, ep);
  tile_sort_kernel<<<NTILE, 512, 0, stream>>>(ep, tts, esp, relofs);

  pack_w_kernel<<<(PACKED_ELEMS + 255) / 256, 256, 0, stream>>>(W, loop_w, WP);
  cvt_bf16_kernel<<<(NN * DIM / 4 + 255) / 256, 256, 0, stream>>>(h0, hb0, NN * DIM / 4);

  rgcn_layer_kernel<<<NTILE, 512, 0, stream>>>(hb0, WP, bias, 0, relofs, esp,
                                               nullptr, hb1);
  rgcn_layer_kernel<<<NTILE, 512, 0, stream>>>(hb1, WP, bias + DIM, 1, relofs, esp,
                                               out, nullptr);
}

// Round 6
// 418.881 us; speedup vs baseline: 1.2156x; 1.2156x over previous
//
#include <hip/hip_runtime.h>
#include <hip/hip_bf16.h>
#include <stdint.h>

// GNN_758: stacked RelGraphConv x2.  N=50000, E=1.6M, D=128, R=20.
// agg[dst] = sum_r (sum_{e in rel r -> dst} h[src]) @ W[r]; self-loop = rel 20.
// R13: revert R12's MFMA-indicator layer (regressed: 2e7 bank conflicts from
// tr-read-constrained staging + 1-MFMA-per-barrier schedule). Back to R11
// scalar-gather layer + NEW phase-1 work-stealing: per chunk, the 80 (dst,rl)
// cells are pulled from an LDS counter by free 16-lane groups (leader
// atomicAdd + shfl broadcast) -> barrier waits on balanced totals, not the
// max of a fixed skewed split (rl{0,1}=2/5 vs rl{2,3,4}=3/5 of edges).
// Preprocessing: R11's two-level LDS counting sort (no device atomics).

#define NN 50000
#define NE 1600000
#define DIM 128
#define NREL 20
#define NRELP 21
#define TILE 16
#define NTILE (NN / TILE)          // 3125
#define CELLS (NN * NREL)          // dst*20 + r
#define CHB 200                    // chunk blocks for count/scatter
#define CHE (NE / CHB)             // 8000 edges per chunk block
#define TT_N (NTILE * CHB)         // 625000 (tile,blk) table
#define SCAN_EPB 2048
#define NBLK_TT ((TT_N + SCAN_EPB - 1) / SCAN_EPB)   // 306
#define SPK_CAP 1024               // staged srcs per block (mean 512, sd ~23)
#define PACKED_ELEMS (2 * NRELP * 4 * 8 * 64 * 8)    // 688128

typedef __attribute__((ext_vector_type(8))) short short8;
typedef __attribute__((ext_vector_type(4))) float f32x4;

__device__ __forceinline__ unsigned short f32_to_bf16_raw(float f) {
  union { float f; unsigned u; } c; c.f = f;
  unsigned u = c.u;
  return (unsigned short)((u + 0x7fffu + ((u >> 16) & 1u)) >> 16);  // RNE
}
__device__ __forceinline__ unsigned cvt_pk_bf16(float lo, float hi) {
  unsigned r;   // bits 0-15 = bf16(lo), 16-31 = bf16(hi), RNE (gfx950)
  asm("v_cvt_pk_bf16_f32 %0, %1, %2" : "=v"(r) : "v"(lo), "v"(hi));
  return r;
}

// ---------------- fp32 -> bf16 (x4), nontemporal stores ----------------
__global__ void cvt_bf16_kernel(const float* __restrict__ in,
                                unsigned short* __restrict__ out, int n4) {
  int i = blockIdx.x * 256 + threadIdx.x;
  if (i < n4) {
    float4 f = ((const float4*)in)[i];
    unsigned long long p =
        (unsigned long long)cvt_pk_bf16(f.x, f.y)
      | ((unsigned long long)cvt_pk_bf16(f.z, f.w) << 32);
    __builtin_nontemporal_store(p, (unsigned long long*)out + i);  // clean -> L3
  }
}

// ---------------- pack W (+loop_w as rel 20) into B-fragment order ----------------
// WP flat: ((((l*21 + r)*4 + ks)*8 + nc)*64 + lane)*8  (verified R0/R1)
__global__ void pack_w_kernel(const float* __restrict__ W,
                              const float* __restrict__ loop_w,
                              unsigned short* __restrict__ WP) {
  int idx = blockIdx.x * 256 + threadIdx.x;
  if (idx >= PACKED_ELEMS) return;
  int j = idx & 7;       int t = idx >> 3;
  int lane = t & 63;     t >>= 6;
  int nc = t & 7;        t >>= 3;
  int ks = t & 3;        t >>= 2;
  int r = t % NRELP;     int l = t / NRELP;
  int k = ks * 32 + (lane >> 4) * 8 + j;
  int n = nc * 16 + (lane & 15);
  float v = (r < NREL) ? W[(((size_t)l * NREL + r) * DIM + k) * DIM + n]
                       : loop_w[((size_t)l * DIM + k) * DIM + n];
  WP[idx] = f32_to_bf16_raw(v);
}

// ---------------- two-level counting sort (no device atomics) ----------------
__global__ __launch_bounds__(256) void tile_count_kernel(
    const int* __restrict__ dst, unsigned int* __restrict__ tt) {
  __shared__ unsigned int hist[NTILE];           // 12.5 KB
  for (int i = threadIdx.x; i < NTILE; i += 256) hist[i] = 0u;
  __syncthreads();
  const int base = blockIdx.x * CHE;
  for (int i = base + threadIdx.x; i < base + CHE; i += 256)
    atomicAdd(&hist[dst[i] >> 4], 1u);           // LDS atomic
  __syncthreads();
  for (int i = threadIdx.x; i < NTILE; i += 256)
    tt[(size_t)i * CHB + blockIdx.x] = hist[i];  // (bin, blk) layout for scan
}

__global__ void scanA_kernel(const unsigned int* __restrict__ in,
                             unsigned int* __restrict__ out,
                             unsigned int* __restrict__ btot, int n) {
  __shared__ unsigned int buf[256];
  int tid = threadIdx.x;
  int base = blockIdx.x * SCAN_EPB + tid * 8;
  unsigned int v[8], p[8], s = 0;
#pragma unroll
  for (int j = 0; j < 8; ++j) {
    v[j] = (base + j < n) ? in[base + j] : 0u;
    p[j] = s; s += v[j];
  }
  buf[tid] = s;
  __syncthreads();
  for (int d = 1; d < 256; d <<= 1) {
    unsigned int a = (tid >= d) ? buf[tid - d] : 0u;
    __syncthreads();
    buf[tid] += a;
    __syncthreads();
  }
  unsigned int excl = buf[tid] - s;
#pragma unroll
  for (int j = 0; j < 8; ++j)
    if (base + j < n) out[base + j] = excl + p[j];
  if (tid == 255) btot[blockIdx.x] = buf[255];
}

__global__ void scanB_kernel(unsigned int* __restrict__ btot, int nblk) {
  __shared__ unsigned int buf[1024];
  int t = threadIdx.x;
  unsigned int v = (t < nblk) ? btot[t] : 0u;
  buf[t] = v;
  __syncthreads();
  for (int d = 1; d < 1024; d <<= 1) {
    unsigned int a = (t >= d) ? buf[t - d] : 0u;
    __syncthreads();
    buf[t] += a;
    __syncthreads();
  }
  if (t < nblk) btot[t] = buf[t] - v;   // exclusive
}

__global__ void scanC_kernel(const unsigned int* __restrict__ btot,
                             unsigned int* __restrict__ out, int n) {
  int base = blockIdx.x * SCAN_EPB + threadIdx.x * 8;
  unsigned int add = btot[blockIdx.x];
#pragma unroll
  for (int j = 0; j < 8; ++j)
    if (base + j < n) out[base + j] += add;
}

// Level-1 scatter: payload u32 = src | dstLow4<<16 | rel<<20, tile-bucketed.
__global__ __launch_bounds__(256) void tile_scatter_kernel(
    const int* __restrict__ src, const int* __restrict__ dst,
    const int* __restrict__ et, const unsigned int* __restrict__ tts,
    unsigned int* __restrict__ ep) {
  __shared__ unsigned int cur[NTILE];            // 12.5 KB
  for (int i = threadIdx.x; i < NTILE; i += 256)
    cur[i] = tts[(size_t)i * CHB + blockIdx.x];
  __syncthreads();
  const int base = blockIdx.x * CHE;
  for (int i = base + threadIdx.x; i < base + CHE; i += 256) {
    int d = dst[i];
    unsigned int pos = atomicAdd(&cur[d >> 4], 1u);   // LDS atomic
    ep[pos] = (unsigned int)src[i] | ((unsigned int)(d & 15) << 16)
            | ((unsigned int)et[i] << 20);
  }
}

// Level 2: per-tile 320-bin sort -> cofs (dst*20+r layout) + es (u16 src).
__global__ __launch_bounds__(512) void tile_sort_kernel(
    const unsigned int* __restrict__ ep, const unsigned int* __restrict__ tts,
    unsigned short* __restrict__ es, unsigned int* __restrict__ cofs) {
  __shared__ unsigned int hist[512];             // 320 bins, padded for scan
  const int t = threadIdx.x;
  const int tile = blockIdx.x;
  const unsigned int start = tts[(size_t)tile * CHB];
  const unsigned int end = (tile + 1 < NTILE) ? tts[(size_t)(tile + 1) * CHB]
                                              : (unsigned int)NE;
  const int cnt = (int)(end - start);
  hist[t] = 0u;
  __syncthreads();
  for (int i = t; i < cnt; i += 512) {
    unsigned int p = ep[start + i];
    atomicAdd(&hist[((p >> 16) & 15u) * 20u + (p >> 20)], 1u);
  }
  __syncthreads();
  unsigned int own = hist[t];
  for (int d = 1; d < 512; d <<= 1) {
    __syncthreads();
    unsigned int a = (t >= d) ? hist[t - d] : 0u;
    __syncthreads();
    hist[t] += a;
  }
  __syncthreads();
  unsigned int excl = hist[t] - own;     // exclusive prefix (own slot only)
  hist[t] = excl;                        // becomes rank cursor
  if (t < 320) cofs[(size_t)tile * 320 + t] = start + excl;
  if (tile == NTILE - 1 && t == 0) cofs[CELLS] = (unsigned int)NE;
  __syncthreads();
  for (int i = t; i < cnt; i += 512) {
    unsigned int p = ep[start + i];
    int sub = (int)(((p >> 16) & 15u) * 20u + (p >> 20));
    unsigned int rk = atomicAdd(&hist[sub], 1u);
    es[start + rk] = (unsigned short)(p & 0xffffu);
  }
}

// ---------------- fused RGCN layer ----------------
// 3125 blocks x 512 threads (8 waves). LDS ~23.3KB -> 4 blocks/CU (wave cap).
__global__ __launch_bounds__(512, 8) void rgcn_layer_kernel(
    const unsigned short* __restrict__ hb,    // [N,128] bf16
    const unsigned short* __restrict__ WP,    // packed weights
    const float* __restrict__ bias,           // [128] this layer
    int layer,
    const unsigned int* __restrict__ cofs,    // [CELLS+1] cell offsets
    const unsigned short* __restrict__ es,    // [E] srcs, cell-sorted
    float* __restrict__ outf,                 // fp32 out (layer 1) or null
    unsigned short* __restrict__ outb)        // bf16 out (layer 0) or null
{
  // Sb: [16 dst rows][5 rl slots * 16 slot16], slot16 = 8 bf16 (16B),
  // slot index ^= (row & 15) -> conflict-free writes and reads (verified R8).
  __shared__ short8 Sb8[TILE * 80];          // 20480 B
  __shared__ unsigned int cofs_l[321];       // 1284 B
  __shared__ unsigned short spk[SPK_CAP];    // 2048 B
  __shared__ unsigned int ctr[4];            // work-steal counters, chunk 0..3

  const int tid  = threadIdx.x;
  const int lane = tid & 63;
  const int w    = tid >> 6;        // wave 0..7
  const int quad = lane >> 4;
  const int m    = lane & 15;
  const int mh8  = m * 8;
  const int g    = (w & 3) * 4 + quad;   // group id for self-loop chunk
  const int dst_base = blockIdx.x * TILE;

  for (int i = tid; i < 321; i += 512) cofs_l[i] = cofs[blockIdx.x * (TILE * NREL) + i];
  if (tid < 4) ctr[tid] = 0u;
  __syncthreads();
  const int e0 = (int)cofs_l[0];
  const int etot = (int)cofs_l[320] - e0;
  const bool use_lds = (etot <= SPK_CAP);
  if (use_lds)
    for (int i = tid; i < etot; i += 512) spk[i] = es[e0 + i];
  __syncthreads();

  f32x4 acc = (f32x4){0.f, 0.f, 0.f, 0.f};

  for (int c = 0; c < 5; ++c) {
    // ---- phase 1: work-stealing over the chunk's 80 (dst,rl) cells ----
    if (c < 4) {
      for (;;) {
        int k0 = 0;
        if (m == 0) k0 = (int)atomicAdd(&ctr[c], 1u);   // group leader pulls
        const int k = __shfl(k0, quad << 4);            // broadcast in group
        if (k >= 80) break;
        const int dd = k & 15;          // dst local
        const int rl = k >> 4;          // 0..4
        const int idx = dd * NREL + c * 5 + rl;
        const int beg = (int)cofs_l[idx] - e0;
        const int end = (int)cofs_l[idx + 1] - e0;

        float a0 = 0.f, a1 = 0.f, a2 = 0.f, a3 = 0.f;
        float a4 = 0.f, a5 = 0.f, a6 = 0.f, a7 = 0.f;
        auto add8 = [&](short8 hv) {
          union { short8 s; uint4 u; } cv; cv.s = hv;
          a0 += __uint_as_float(cv.u.x << 16);
          a1 += __uint_as_float(cv.u.x & 0xffff0000u);
          a2 += __uint_as_float(cv.u.y << 16);
          a3 += __uint_as_float(cv.u.y & 0xffff0000u);
          a4 += __uint_as_float(cv.u.z << 16);
          a5 += __uint_as_float(cv.u.z & 0xffff0000u);
          a6 += __uint_as_float(cv.u.w << 16);
          a7 += __uint_as_float(cv.u.w & 0xffff0000u);
        };
        auto walk = [&](auto fetch) {
          for (int i = beg; i < end; i += 4) {
            const int nrem = end - i;
            short8 h0, h1, h2, h3;
            h0 = fetch(i);
            if (nrem > 1) h1 = fetch(i + 1);
            if (nrem > 2) h2 = fetch(i + 2);
            if (nrem > 3) h3 = fetch(i + 3);
            add8(h0);
            if (nrem > 1) add8(h1);
            if (nrem > 2) add8(h2);
            if (nrem > 3) add8(h3);
          }
        };
        if (use_lds) {
          walk([&](int i) {
            return *(const short8*)(hb + (size_t)spk[i] * DIM + mh8);
          });
        } else {
          walk([&](int i) {
            return *(const short8*)(hb + (size_t)es[e0 + i] * DIM + mh8);
          });
        }
        union { uint4 u; short8 s; } pk;
        pk.u.x = cvt_pk_bf16(a0, a1);
        pk.u.y = cvt_pk_bf16(a2, a3);
        pk.u.z = cvt_pk_bf16(a4, a5);
        pk.u.w = cvt_pk_bf16(a6, a7);
        Sb8[dd * 80 + ((rl * 16 + m) ^ dd)] = pk.s;
      }
    } else if (w < 4) {
      // self-loop mini-chunk: group g handles own row (feeds rel 20 = loop_w)
      short8 hv = *(const short8*)(hb + (size_t)(dst_base + g) * DIM + mh8);
      Sb8[g * 80 + (m ^ g)] = hv;   // already bf16; sum of one row
    }
    __syncthreads();

    // ---- phase 2: nc-split 8 ways. wave w owns cols [16w,16w+16) ----
    const int rc = (c == 4) ? 1 : 5;
    for (int rl2 = 0; rl2 < rc; ++rl2) {
      const int r = (c == 4) ? (NRELP - 1) : (c * 5 + rl2);
      const unsigned short* bp =
          WP + ((((size_t)(layer * NRELP + r) * 4) * 8 + w) * 64 + lane) * 8;
#pragma unroll
      for (int ks = 0; ks < 4; ++ks) {
        short8 a = Sb8[m * 80 + ((rl2 * 16 + ks * 4 + quad) ^ m)];
        short8 b = *(const short8*)(bp + (size_t)ks * 4096);
        acc = __builtin_amdgcn_mfma_f32_16x16x32_bf16(a, b, acc, 0, 0, 0);
      }
    }
    __syncthreads();
  }

  // ---- epilogue: wave w stores its 16-col tile; no cross-wave reduction ----
  const int col = w * 16 + m;
  const float bv = bias[col];
  if (outb) {
#pragma unroll
    for (int i = 0; i < 4; ++i)
      outb[(size_t)(dst_base + quad * 4 + i) * DIM + col] =
          f32_to_bf16_raw(acc[i] + bv);
  } else {
#pragma unroll
    for (int i = 0; i < 4; ++i)
      outf[(size_t)(dst_base + quad * 4 + i) * DIM + col] = acc[i] + bv;
  }
}

// ---------------- launch ----------------
extern "C" void kernel_launch(void* const* d_in, const int* in_sizes, int n_in,
                              void* d_out, int out_size, void* d_ws, size_t ws_size,
                              hipStream_t stream) {
  const float* h0     = (const float*)d_in[0];
  const float* W      = (const float*)d_in[1];
  const float* loop_w = (const float*)d_in[2];
  const float* bias   = (const float*)d_in[3];
  const int* esrc     = (const int*)d_in[4];
  const int* edst     = (const int*)d_in[5];
  const int* etyp     = (const int*)d_in[6];
  float* out = (float*)d_out;

  char* ws = (char*)d_ws;
  size_t off = 0;
  auto alloc = [&](size_t bytes) -> void* {
    void* p = ws + off;
    off = (off + bytes + 255) & ~(size_t)255;
    return p;
  };
  unsigned short* hb0   = (unsigned short*)alloc((size_t)NN * DIM * 2);   // 12.8 MB
  unsigned short* hb1   = (unsigned short*)alloc((size_t)NN * DIM * 2);   // 12.8 MB
  unsigned short* WP    = (unsigned short*)alloc((size_t)PACKED_ELEMS * 2);
  unsigned int*   tt    = (unsigned int*)alloc((size_t)(TT_N + 1) * 4);   // 2.5 MB
  unsigned int*   tts   = (unsigned int*)alloc((size_t)(TT_N + 1) * 4);   // 2.5 MB
  unsigned int*   btot  = (unsigned int*)alloc((size_t)NBLK_TT * 4);
  unsigned int*   ep    = (unsigned int*)alloc((size_t)NE * 4);           // 6.4 MB
  unsigned int*   cofs  = (unsigned int*)alloc((size_t)(CELLS + 1) * 4);  // 4 MB
  unsigned short* es    = (unsigned short*)alloc((size_t)NE * 2);         // 3.2 MB

  tile_count_kernel<<<CHB, 256, 0, stream>>>(edst, tt);
  scanA_kernel<<<NBLK_TT, 256, 0, stream>>>(tt, tts, btot, TT_N);
  scanB_kernel<<<1, 1024, 0, stream>>>(btot, NBLK_TT);
  scanC_kernel<<<NBLK_TT, 256, 0, stream>>>(btot, tts, TT_N);
  tile_scatter_kernel<<<CHB, 256, 0, stream>>>(esrc, edst, etyp, tts, ep);
  tile_sort_kernel<<<NTILE, 512, 0, stream>>>(ep, tts, es, cofs);

  pack_w_kernel<<<(PACKED_ELEMS + 255) / 256, 256, 0, stream>>>(W, loop_w, WP);
  cvt_bf16_kernel<<<(NN * DIM / 4 + 255) / 256, 256, 0, stream>>>(h0, hb0, NN * DIM / 4);

  rgcn_layer_kernel<<<NTILE, 512, 0, stream>>>(hb0, WP, bias, 0, cofs, es,
                                               nullptr, hb1);
  rgcn_layer_kernel<<<NTILE, 512, 0, stream>>>(hb1, WP, bias + DIM, 1, cofs, es,
                                               out, nullptr);
}